// Round 6
// baseline (137.554 us; speedup 1.0000x reference)
//
#include <hip/hip_runtime.h>
#include <cstddef>
#include <cstdint>

// Problem constants (from reference setup_inputs)
#define T_DIM 500
#define B_DIM 32
#define C_DIM 1024
#define O_DIM 1024
#define M_DIM (T_DIM * B_DIM)   // 16000
#define MP_DIM 16128            // padded to 63*256
#define BO_DIM (B_DIM * O_DIM)  // 32768

typedef __attribute__((ext_vector_type(8))) short bf16x8;
typedef __attribute__((ext_vector_type(4))) float f32x4;

static __device__ __forceinline__ ushort f2bf(float x) {
  unsigned u = __float_as_uint(x);
  return (ushort)((u + 0x7FFF + ((u >> 16) & 1)) >> 16);  // RNE
}
static __device__ __forceinline__ float bf2f(ushort u) {
  return __uint_as_float(((unsigned)u) << 16);
}

// Inline-asm ds_read_b128 (kept from R5: proven correct, within-noise perf).
static __device__ __forceinline__ bf16x8 ldsr(const ushort* p) {
  bf16x8 d;
  asm volatile("ds_read_b128 %0, %1"
               : "=v"(d)
               : "v"((unsigned)(uintptr_t)(const __attribute__((address_space(3))) ushort*)p));
  return d;
}

// ---------------------------------------------------------------------------
// K0: transpose + cast x[B, C, T] fp32 -> xt[(t*B + b), c] bf16 ([MP, C])
// ---------------------------------------------------------------------------
__global__ __launch_bounds__(256) void k_transpose(const float* __restrict__ x,
                                                   ushort* __restrict__ xt) {
  __shared__ float tile[32][33];
  const int b  = blockIdx.z;
  const int t0 = blockIdx.x * 32;
  const int c0 = blockIdx.y * 32;
  const int tx = threadIdx.x;      // 0..31
  const int ty = threadIdx.y;      // 0..7

  const int t = t0 + tx;
  if (t < T_DIM) {
#pragma unroll
    for (int r = 0; r < 4; ++r) {
      const int c = c0 + ty + r * 8;
      tile[ty + r * 8][tx] = x[((size_t)b * C_DIM + c) * T_DIM + t];
    }
  }
  __syncthreads();
#pragma unroll
  for (int r = 0; r < 4; ++r) {
    const int tt = t0 + ty + r * 8;
    if (tt < T_DIM) {
      xt[((size_t)tt * B_DIM + b) * C_DIM + c0 + tx] = f2bf(tile[tx][ty + r * 8]);
    }
  }
}

// ---------------------------------------------------------------------------
// KW: cast W[O, C] fp32 -> bf16
// ---------------------------------------------------------------------------
__global__ __launch_bounds__(256) void k_cast_w(const float4* __restrict__ W,
                                                ushort* __restrict__ Wb) {
  const int i = blockIdx.x * 256 + threadIdx.x;   // over O*C/4
  const float4 w = W[i];
  ushort* o = Wb + (size_t)i * 4;
  o[0] = f2bf(w.x); o[1] = f2bf(w.y); o[2] = f2bf(w.z); o[3] = f2bf(w.w);
}

// ---------------------------------------------------------------------------
// K1: bf16 MFMA GEMM (NT): v[MP, O] = xt[MP, K] * Wb[O, K]^T, bf16 out.
// R6 change: 1024 threads (16 waves, 4Mx4N, wave tile 64x64), 1 block/CU
// => 252 blocks cover 252/256 CUs (was: 512 thr, 2/CU => only 126 CUs).
// Same 256x256 tile, BK=64, 2-slot LDS ring, 4 phases/K-tile, counted vmcnt
// (now 4 loads/wave/tile), involution k-swizzle, setprio on MFMA clusters.
//
// Race-freedom:
//  - ph1 opens with per-wave vmcnt(4) [only tile t+1's 4 loads outstanding]
//    + barrier => tile t fully landed for all waves. t==15: vmcnt(0).
//  - ph1 reads ALL a-frags + b0; ph2 reads b1; ph2 ends lgkmcnt(0)+barrier
//    => slot fully consumed before ph3/ph4 stage tile t+2 into it.
// ---------------------------------------------------------------------------
__global__ __launch_bounds__(1024, 4) void k_gemm_bf16(const ushort* __restrict__ A,
                                                       const ushort* __restrict__ Bw,
                                                       ushort* __restrict__ C) {
  // [slot:2][mat:2(A,B)][rowhalf:2][khalf:2][r:128][k:32] bf16, swizzled k
  __shared__ ushort lds[65536];  // 128 KiB

  const int tid  = threadIdx.x;
  const int wid  = tid >> 6;       // 0..15
  const int lane = tid & 63;

  // bijective XCD chunk swizzle (m204): nwg=252, q=31, r=4
  const int orig = blockIdx.x;
  const int xcd  = orig & 7;
  const int base = (xcd < 4) ? xcd * 32 : 128 + (xcd - 4) * 31;
  const int wgid = base + (orig >> 3);
  const int row0 = (wgid >> 2) * 256;   // 63 row tiles (col-fast => A L2 reuse)
  const int col0 = (wgid & 3) * 256;    // 4 col tiles

  const int wm = wid >> 2;         // 0..3 : wave row-quarter (64 rows)
  const int wn = wid & 3;          // 0..3 : wave col-quarter (64 cols)

  f32x4 acc[4][4] = {};            // [m-frag][n-frag]

  // ---- staging (per-thread): covers LDS ushort offset rh*8192 + tid*8 ----
  // decode: kh = tid>>9, r = (tid>>2)&127, k0 = (tid&3)*8; swizzle bit = row
  // bit3 = (tid>>5)&1, pre-applied to the GLOBAL source k (LDS stays linear).
  const int kh  = tid >> 9;
  const int rin = (tid >> 2) & 127;
  const int sk  = ((tid & 3) * 8) ^ (((tid >> 5) & 1) << 4);
  const ushort* Abase = A  + (size_t)(row0 + rin) * C_DIM + kh * 32 + sk;
  const ushort* Bbase = Bw + (size_t)(col0 + rin) * C_DIM + kh * 32 + sk;

  // ---- fragment read offsets (matching involution: row bit3 = fr bit3) ----
  const int fr  = lane & 15;
  const int fko = ((lane >> 4) * 8) ^ (((lane >> 3) & 1) << 4);
  const int aoff = (wm >> 1) * 8192 + ((wm & 1) * 64 + fr) * 32 + fko;          // + h*4096 + i*512
  const int boff = 16384 + (wn >> 1) * 8192 + ((wn & 1) * 64 + fr) * 32 + fko;  // + h*4096 + j*512

#define STAGE_A(K0S, SB)                                                          \
  _Pragma("unroll")                                                               \
  for (int rh = 0; rh < 2; ++rh)                                                  \
    __builtin_amdgcn_global_load_lds(                                             \
        (const __attribute__((address_space(1))) void*)(Abase + (size_t)rh * 128 * C_DIM + (K0S)), \
        (__attribute__((address_space(3))) void*)&lds[(SB) + rh * 8192 + wid * 512], 16, 0, 0)

#define STAGE_B(K0S, SB)                                                          \
  _Pragma("unroll")                                                               \
  for (int rh = 0; rh < 2; ++rh)                                                  \
    __builtin_amdgcn_global_load_lds(                                             \
        (const __attribute__((address_space(1))) void*)(Bbase + (size_t)rh * 128 * C_DIM + (K0S)), \
        (__attribute__((address_space(3))) void*)&lds[(SB) + 16384 + rh * 8192 + wid * 512], 16, 0, 0)

  // prologue: stage tiles 0 and 1 (4 loads/wave each)
  STAGE_A(0, 0);
  STAGE_B(0, 0);
  STAGE_A(64, 32768);
  STAGE_B(64, 32768);

  for (int t = 0; t < 16; ++t) {
    const int sb = (t & 1) * 32768;
    bf16x8 a[4][2], b0[2][2], b1[2][2];

    // ---------- ph1: ALL a-frags + b0; MFMA (i0-1 x j0-1) ----------
    if (t < 15) { asm volatile("s_waitcnt vmcnt(4)" ::: "memory"); }
    else        { asm volatile("s_waitcnt vmcnt(0)" ::: "memory"); }
    __builtin_amdgcn_s_barrier();                      // tile t landed, all waves
#pragma unroll
    for (int i = 0; i < 4; ++i)
#pragma unroll
      for (int h = 0; h < 2; ++h)
        a[i][h] = ldsr(&lds[sb + aoff + h * 4096 + i * 512]);
#pragma unroll
    for (int j = 0; j < 2; ++j)
#pragma unroll
      for (int h = 0; h < 2; ++h)
        b0[j][h] = ldsr(&lds[sb + boff + h * 4096 + j * 512]);
    asm volatile("s_waitcnt lgkmcnt(0)" ::: "memory");
    __builtin_amdgcn_sched_barrier(0);
    __builtin_amdgcn_s_setprio(1);
#pragma unroll
    for (int i = 0; i < 2; ++i)
#pragma unroll
      for (int j = 0; j < 2; ++j)
#pragma unroll
        for (int h = 0; h < 2; ++h)
          acc[i][j] = __builtin_amdgcn_mfma_f32_16x16x32_bf16(a[i][h], b0[j][h], acc[i][j], 0, 0, 0);
    __builtin_amdgcn_s_setprio(0);
    __builtin_amdgcn_s_barrier();

    // ---------- ph2: b1 frags; MFMA (i2-3 x j0-1) ----------
#pragma unroll
    for (int j = 0; j < 2; ++j)
#pragma unroll
      for (int h = 0; h < 2; ++h)
        b1[j][h] = ldsr(&lds[sb + boff + h * 4096 + (2 + j) * 512]);
    asm volatile("s_waitcnt lgkmcnt(0)" ::: "memory");
    __builtin_amdgcn_sched_barrier(0);
    __builtin_amdgcn_s_setprio(1);
#pragma unroll
    for (int i = 2; i < 4; ++i)
#pragma unroll
      for (int j = 0; j < 2; ++j)
#pragma unroll
        for (int h = 0; h < 2; ++h)
          acc[i][j] = __builtin_amdgcn_mfma_f32_16x16x32_bf16(a[i][h], b0[j][h], acc[i][j], 0, 0, 0);
    __builtin_amdgcn_s_setprio(0);
    __builtin_amdgcn_s_barrier();          // ALL slot reads for tile t done

    // ---------- ph3: stage A(t+2) into this slot; MFMA (i0-1 x j2-3) ------
    if (t < 14) { STAGE_A((t + 2) * 64, sb); }
    __builtin_amdgcn_s_setprio(1);
#pragma unroll
    for (int i = 0; i < 2; ++i)
#pragma unroll
      for (int j = 0; j < 2; ++j)
#pragma unroll
        for (int h = 0; h < 2; ++h)
          acc[i][2 + j] = __builtin_amdgcn_mfma_f32_16x16x32_bf16(a[i][h], b1[j][h], acc[i][2 + j], 0, 0, 0);
    __builtin_amdgcn_s_setprio(0);
    __builtin_amdgcn_s_barrier();

    // ---------- ph4: stage B(t+2); MFMA (i2-3 x j2-3) ---------------------
    if (t < 14) { STAGE_B((t + 2) * 64, sb); }
    __builtin_amdgcn_s_setprio(1);
#pragma unroll
    for (int i = 2; i < 4; ++i)
#pragma unroll
      for (int j = 0; j < 2; ++j)
#pragma unroll
        for (int h = 0; h < 2; ++h)
          acc[i][2 + j] = __builtin_amdgcn_mfma_f32_16x16x32_bf16(a[i][h], b1[j][h], acc[i][2 + j], 0, 0, 0);
    __builtin_amdgcn_s_setprio(0);
    __builtin_amdgcn_s_barrier();
  }

  // epilogue: C/D layout col = lane&15, row = (lane>>4)*4 + reg  [m89]
  const int crow = (lane >> 4) * 4;
  const int ccol = lane & 15;
#pragma unroll
  for (int i = 0; i < 4; ++i)
#pragma unroll
    for (int j = 0; j < 4; ++j) {
      ushort* cp = C + (size_t)(row0 + wm * 64 + i * 16 + crow) * O_DIM
                     + (col0 + wn * 64 + j * 16 + ccol);
#pragma unroll
      for (int r = 0; r < 4; ++r) cp[(size_t)r * O_DIM] = f2bf(acc[i][j][r]);
    }
#undef STAGE_A
#undef STAGE_B
}

// ---------------------------------------------------------------------------
// K2: fused PSP alpha-filter + refractory spike scan (bf16 v input).
// One thread per (b, o); 64-thr (1-wave) blocks, 512 blocks.
// R6 change: spikes are 0/1 -> pack 32 t-steps per u32 into LDS, then write
// out[] fully COALESCED (2KB contiguous per row) instead of per-thread
// strided float4 (adjacent threads were 2KB apart).
// Chunks of D=32 so bit position == unrolled j (compile-time); tail loads
// clamped to t=499 (values discarded).
// ---------------------------------------------------------------------------
__global__ __launch_bounds__(64) void k_scan(const ushort* __restrict__ v,
                                             float* __restrict__ out) {
  __shared__ unsigned wbits[64][16];   // [thread][t-word]
  const int l  = threadIdx.x;
  const int g0 = blockIdx.x * 64;

  const float a1 = 0.90483741803595952f;   // exp(-TS/TAU_SR)
  const float c1 = 0.27182818284590452f;   // e*TS/TAU_SR
  const float a2 = 0.36787944117144233f;   // exp(-TS/TAU_REF)
  const float c2 = -54.365636569180905f;   // -SCALE_REF*THETA*e*TS/TAU_REF

  float p1 = 0.f, q1 = 0.f;
  float p2 = 0.f, q2 = 0.f;

  const ushort* vp = v + g0 + l;

  constexpr int D  = 32;   // t-steps per chunk (= bits per word)
  constexpr int NC = 16;   // 512 >= 500; tail loads clamped

  ushort b0[D], b1[D], b2[D];
#pragma unroll
  for (int j = 0; j < D; ++j) b0[j] = vp[(size_t)j * BO_DIM];
#pragma unroll
  for (int j = 0; j < D; ++j) b1[j] = vp[(size_t)(D + j) * BO_DIM];
#pragma unroll
  for (int j = 0; j < D; ++j) b2[j] = vp[(size_t)(2 * D + j) * BO_DIM];

#pragma unroll 4
  for (int c = 0; c < NC; ++c) {
    const int cn = (c + 3 < NC) ? (c + 3) : (NC - 1);
    ushort bn[D];
#pragma unroll
    for (int j = 0; j < D; ++j) {
      int t = cn * D + j;
      if (t > 499) t = 499;              // clamp: redundant L2-hot re-load
      bn[j] = vp[(size_t)t * BO_DIM];
    }

    unsigned curw = 0;
#pragma unroll
    for (int j = 0; j < D; ++j) {
      const float vn = bf2f(b0[j]);
      q1 = a1 * q1 + a1 * p1;
      p1 = a1 * p1 + vn;
      const float u = c1 * q1;
      q2 = a2 * q2 + a2 * p2;
      const bool fire = (u + c2 * q2 >= 10.0f);
      p2 = a2 * p2 + (fire ? 1.0f : 0.0f);
      curw |= (unsigned)fire << j;       // j compile-time
    }
    wbits[l][c] = curw;

#pragma unroll
    for (int j = 0; j < D; ++j) { b0[j] = b1[j]; b1[j] = b2[j]; b2[j] = bn[j]; }
  }
  __syncthreads();

  // coalesced write phase: rows g0..g0+63, 500 floats (2KB) each
  for (int r = 0; r < 64; ++r) {
    float* orow = out + (size_t)(g0 + r) * T_DIM;
#pragma unroll
    for (int wv = 0; wv < 2; ++wv) {
      const int w = wv * 64 + l;         // float4 index 0..124
      if (w < 125) {
        const int t0 = w * 4;
        const unsigned word = wbits[r][t0 >> 5];
        const unsigned sh = (unsigned)(t0 & 31);
        float4 f;
        f.x = ((word >> (sh + 0)) & 1u) ? 1.0f : 0.0f;
        f.y = ((word >> (sh + 1)) & 1u) ? 1.0f : 0.0f;
        f.z = ((word >> (sh + 2)) & 1u) ? 1.0f : 0.0f;
        f.w = ((word >> (sh + 3)) & 1u) ? 1.0f : 0.0f;
        *(float4*)&orow[t0] = f;
      }
    }
  }
}

// ---------------------------------------------------------------------------
extern "C" void kernel_launch(void* const* d_in, const int* in_sizes, int n_in,
                              void* d_out, int out_size, void* d_ws, size_t ws_size,
                              hipStream_t stream) {
  const float* x = (const float*)d_in[0];  // [B, C, 1, 1, T] fp32 (binary)
  const float* W = (const float*)d_in[1];  // [O, C] fp32
  float* out = (float*)d_out;              // [B, O, 1, 1, T] fp32

  ushort* v  = (ushort*)d_ws;                         // [MP, O] bf16, 33 MB
  ushort* xt = v + (size_t)MP_DIM * O_DIM;            // [MP, C] bf16, 33 MB
  ushort* Wb = xt + (size_t)MP_DIM * C_DIM;           // [O, C] bf16, 2 MB

  // K0: transpose + cast
  dim3 g0((T_DIM + 31) / 32, C_DIM / 32, B_DIM);
  k_transpose<<<g0, dim3(32, 8), 0, stream>>>(x, xt);

  // KW: cast W to bf16
  k_cast_w<<<(O_DIM * C_DIM / 4) / 256, 256, 0, stream>>>((const float4*)W, Wb);

  // K1: v = xt * Wb^T  (256^2 tile, 1024 thr, 1 block/CU, 252 CUs active)
  k_gemm_bf16<<<(MP_DIM / 256) * (O_DIM / 256), 1024, 0, stream>>>(xt, Wb, v);

  // K2: fused filter + spike scan (bit-packed, coalesced writes)
  k_scan<<<BO_DIM / 64, 64, 0, stream>>>(v, out);
}

// Round 7
// 89.581 us; speedup vs baseline: 1.5355x; 1.5355x over previous
//
#include <hip/hip_runtime.h>
#include <cstddef>
#include <cstdint>

// Problem constants (from reference setup_inputs)
#define T_DIM 500
#define B_DIM 32
#define C_DIM 1024
#define O_DIM 1024
#define M_DIM (T_DIM * B_DIM)   // 16000
#define MP_DIM 16128            // padded to 63*256
#define BO_DIM (B_DIM * O_DIM)  // 32768

typedef __attribute__((ext_vector_type(8))) short bf16x8;
typedef __attribute__((ext_vector_type(4))) float f32x4;

static __device__ __forceinline__ ushort f2bf(float x) {
  unsigned u = __float_as_uint(x);
  return (ushort)((u + 0x7FFF + ((u >> 16) & 1)) >> 16);  // RNE
}
static __device__ __forceinline__ float bf2f(ushort u) {
  return __uint_as_float(((unsigned)u) << 16);
}

// Inline-asm ds_read_b128 (proven correct R5; keeps frag reads out of the
// compiler's vmem-dependency tracking so counted vmcnt survives).
static __device__ __forceinline__ bf16x8 ldsr(const ushort* p) {
  bf16x8 d;
  asm volatile("ds_read_b128 %0, %1"
               : "=v"(d)
               : "v"((unsigned)(uintptr_t)(const __attribute__((address_space(3))) ushort*)p));
  return d;
}

// ---------------------------------------------------------------------------
// K0: transpose + cast x[B, C, T] fp32 -> xt[(t*B + b), c] bf16 ([MP, C])
// ---------------------------------------------------------------------------
__global__ __launch_bounds__(256) void k_transpose(const float* __restrict__ x,
                                                   ushort* __restrict__ xt) {
  __shared__ float tile[32][33];
  const int b  = blockIdx.z;
  const int t0 = blockIdx.x * 32;
  const int c0 = blockIdx.y * 32;
  const int tx = threadIdx.x;      // 0..31
  const int ty = threadIdx.y;      // 0..7

  const int t = t0 + tx;
  if (t < T_DIM) {
#pragma unroll
    for (int r = 0; r < 4; ++r) {
      const int c = c0 + ty + r * 8;
      tile[ty + r * 8][tx] = x[((size_t)b * C_DIM + c) * T_DIM + t];
    }
  }
  __syncthreads();
#pragma unroll
  for (int r = 0; r < 4; ++r) {
    const int tt = t0 + ty + r * 8;
    if (tt < T_DIM) {
      xt[((size_t)tt * B_DIM + b) * C_DIM + c0 + tx] = f2bf(tile[tx][ty + r * 8]);
    }
  }
}

// ---------------------------------------------------------------------------
// KW: cast W[O, C] fp32 -> bf16
// ---------------------------------------------------------------------------
__global__ __launch_bounds__(256) void k_cast_w(const float4* __restrict__ W,
                                                ushort* __restrict__ Wb) {
  const int i = blockIdx.x * 256 + threadIdx.x;   // over O*C/4
  const float4 w = W[i];
  ushort* o = Wb + (size_t)i * 4;
  o[0] = f2bf(w.x); o[1] = f2bf(w.y); o[2] = f2bf(w.z); o[3] = f2bf(w.w);
}

// ---------------------------------------------------------------------------
// K1: bf16 MFMA GEMM (NT): v[MP, O] = xt[MP, K] * Wb[O, K]^T, bf16 out.
// R7 geometry: BM=256, BN=128, BK=32; 512 threads (8 waves, 4Mx2N, wave-tile
// 64x64); grid 63x8 = 504 blocks; LDS 48 KB (2-slot ring) => 2 blocks/CU
// co-resident => 252 CUs active with 16 waves each (R6's occupancy goal
// WITHOUT the VGPR spill: ~120 regs/thread, launch_bounds(512,4)).
// Schedule per K-tile (2 barriers, counted vmcnt, never drained mid-loop):
//   vmcnt(3)+bar  -> tile t landed (only t+1's 3 loads outstanding)
//   8x ds_read all frags; lgkmcnt(0); bar -> slot fully consumed
//   stage tile t+2 into this slot (3 loads) ; setprio(1) 16 MFMA setprio(0)
// ---------------------------------------------------------------------------
__global__ __launch_bounds__(512, 4) void k_gemm_bf16(const ushort* __restrict__ A,
                                                      const ushort* __restrict__ Bw,
                                                      ushort* __restrict__ C) {
  // slot layout (ushorts): A [r:256][k:32] = 8192, B [r:128][k:32] = 4096
  // slot stride 12288 (24 KB); 2 slots = 48 KB. k pre-swizzled (row bit3).
  __shared__ ushort lds[24576];

  const int tid  = threadIdx.x;
  const int wid  = tid >> 6;       // 0..7
  const int lane = tid & 63;

  // XCD swizzle: 504 = 8*63, xcd k owns 63 consecutive logical tiles
  const int orig = blockIdx.x;
  const int swz  = (orig & 7) * 63 + (orig >> 3);
  const int row0 = (swz >> 3) * 256;   // 63 row panels
  const int col0 = (swz & 7) * 128;    // 8 col panels (col-fast => A L2 reuse)

  const int wm = wid >> 1;         // 0..3 : wave row-quarter (64 rows)
  const int wn = wid & 1;          // 0..1 : wave col-half    (64 cols)

  f32x4 acc[4][4] = {};            // [m-frag][n-frag]

  // ---- staging source (per-thread, k pre-swizzled by row bit3) ----
  const int srow = tid >> 2;                                  // 0..127
  const int sk   = ((tid & 3) * 8) ^ (((tid >> 5) & 1) << 4); // row bit3 = (tid>>5)&1
  const ushort* Abase = A  + (size_t)(row0 + srow) * C_DIM + sk;
  const ushort* Bbase = Bw + (size_t)(col0 + srow) * C_DIM + sk;

  // ---- fragment read offsets (matching involution: row bit3 = fr bit3) ----
  const int fr  = lane & 15;
  const int fko = ((lane >> 4) * 8) ^ (((lane >> 3) & 1) << 4);
  const int aoff = (wm * 64 + fr) * 32 + fko;          // + i*512
  const int boff = 8192 + (wn * 64 + fr) * 32 + fko;   // + j*512

#define STAGE_A(K0S, SB)                                                          \
  _Pragma("unroll")                                                               \
  for (int rh = 0; rh < 2; ++rh)                                                  \
    __builtin_amdgcn_global_load_lds(                                             \
        (const __attribute__((address_space(1))) void*)(Abase + (size_t)rh * 128 * C_DIM + (K0S)), \
        (__attribute__((address_space(3))) void*)&lds[(SB) + rh * 4096 + wid * 512], 16, 0, 0)

#define STAGE_B(K0S, SB)                                                          \
  __builtin_amdgcn_global_load_lds(                                               \
      (const __attribute__((address_space(1))) void*)(Bbase + (K0S)),             \
      (__attribute__((address_space(3))) void*)&lds[(SB) + 8192 + wid * 512], 16, 0, 0)

  // prologue: stage tiles 0 and 1 (3 loads/thread each)
  STAGE_A(0, 0);
  STAGE_B(0, 0);
  STAGE_A(32, 12288);
  STAGE_B(32, 12288);

  for (int t = 0; t < 32; ++t) {
    const int sb = (t & 1) * 12288;
    bf16x8 a[4], b[4];

    // tile t landed: only tile t+1's 3 loads may remain outstanding
    if (t < 31) { asm volatile("s_waitcnt vmcnt(3)" ::: "memory"); }
    else        { asm volatile("s_waitcnt vmcnt(0)" ::: "memory"); }
    __builtin_amdgcn_s_barrier();

    // read ALL fragments of this slot
#pragma unroll
    for (int i = 0; i < 4; ++i) a[i] = ldsr(&lds[sb + aoff + i * 512]);
#pragma unroll
    for (int j = 0; j < 4; ++j) b[j] = ldsr(&lds[sb + boff + j * 512]);
    asm volatile("s_waitcnt lgkmcnt(0)" ::: "memory");
    __builtin_amdgcn_sched_barrier(0);
    __builtin_amdgcn_s_barrier();      // all waves done reading this slot

    // stage tile t+2 into this slot (overlaps with MFMA below)
    if (t < 30) {
      STAGE_A((t + 2) * 32, sb);
      STAGE_B((t + 2) * 32, sb);
    }

    __builtin_amdgcn_s_setprio(1);
#pragma unroll
    for (int i = 0; i < 4; ++i)
#pragma unroll
      for (int j = 0; j < 4; ++j)
        acc[i][j] = __builtin_amdgcn_mfma_f32_16x16x32_bf16(a[i], b[j], acc[i][j], 0, 0, 0);
    __builtin_amdgcn_s_setprio(0);
  }

  // epilogue: C/D layout col = lane&15, row = (lane>>4)*4 + reg  [m89]
  const int crow = (lane >> 4) * 4;
  const int ccol = lane & 15;
#pragma unroll
  for (int i = 0; i < 4; ++i)
#pragma unroll
    for (int j = 0; j < 4; ++j) {
      ushort* cp = C + (size_t)(row0 + wm * 64 + i * 16 + crow) * O_DIM
                     + (col0 + wn * 64 + j * 16 + ccol);
#pragma unroll
      for (int r = 0; r < 4; ++r) cp[(size_t)r * O_DIM] = f2bf(acc[i][j][r]);
    }
#undef STAGE_A
#undef STAGE_B
}

// ---------------------------------------------------------------------------
// K2: fused PSP alpha-filter + refractory spike scan (bf16 v input).
// One thread per (b, o); 64-thr blocks (512 blocks, all CUs); 3-chunk-deep
// register prefetch (D=20: 60 ushorts of buffer, no spill); static indices.
// (R5 version — R6's D=32 bit-pack variant spilled and regressed.)
// ---------------------------------------------------------------------------
__global__ __launch_bounds__(64) void k_scan(const ushort* __restrict__ v,
                                             float* __restrict__ out) {
  const int g = blockIdx.x * 64 + threadIdx.x;  // b*O + o

  const float a1 = 0.90483741803595952f;   // exp(-TS/TAU_SR)
  const float c1 = 0.27182818284590452f;   // e*TS/TAU_SR
  const float a2 = 0.36787944117144233f;   // exp(-TS/TAU_REF)
  const float c2 = -54.365636569180905f;   // -SCALE_REF*THETA*e*TS/TAU_REF

  float p1 = 0.f, q1 = 0.f;
  float p2 = 0.f, q2 = 0.f;

  const ushort* vp = v + g;
  float* op = out + (size_t)g * T_DIM;

  constexpr int D  = 20;   // t-steps per chunk
  constexpr int NC = 25;   // chunks (D*NC = 500)

  ushort b0[D], b1[D], b2[D];
#pragma unroll
  for (int j = 0; j < D; ++j) b0[j] = vp[(size_t)j * BO_DIM];
#pragma unroll
  for (int j = 0; j < D; ++j) b1[j] = vp[(size_t)(D + j) * BO_DIM];
#pragma unroll
  for (int j = 0; j < D; ++j) b2[j] = vp[(size_t)(2 * D + j) * BO_DIM];

#pragma unroll 5
  for (int c = 0; c < NC; ++c) {
    const int cn = (c + 3 < NC) ? (c + 3) : (NC - 1);
    ushort bn[D];
    {
      const size_t base = (size_t)cn * D;
#pragma unroll
      for (int j = 0; j < D; ++j) bn[j] = vp[(base + j) * BO_DIM];
    }

    float rr[D];
#pragma unroll
    for (int j = 0; j < D; ++j) {
      const float vn = bf2f(b0[j]);
      q1 = a1 * q1 + a1 * p1;
      p1 = a1 * p1 + vn;
      const float u = c1 * q1;
      q2 = a2 * q2 + a2 * p2;
      const float s = (u + c2 * q2 >= 10.0f) ? 1.0f : 0.0f;
      p2 = a2 * p2 + s;
      rr[j] = s;
    }

    float* o = op + c * D;
#pragma unroll
    for (int j = 0; j < D; j += 4)
      *(float4*)&o[j] = make_float4(rr[j], rr[j + 1], rr[j + 2], rr[j + 3]);

#pragma unroll
    for (int j = 0; j < D; ++j) { b0[j] = b1[j]; b1[j] = b2[j]; b2[j] = bn[j]; }
  }
}

// ---------------------------------------------------------------------------
extern "C" void kernel_launch(void* const* d_in, const int* in_sizes, int n_in,
                              void* d_out, int out_size, void* d_ws, size_t ws_size,
                              hipStream_t stream) {
  const float* x = (const float*)d_in[0];  // [B, C, 1, 1, T] fp32 (binary)
  const float* W = (const float*)d_in[1];  // [O, C] fp32
  float* out = (float*)d_out;              // [B, O, 1, 1, T] fp32

  ushort* v  = (ushort*)d_ws;                         // [MP, O] bf16, 33 MB
  ushort* xt = v + (size_t)MP_DIM * O_DIM;            // [MP, C] bf16, 33 MB
  ushort* Wb = xt + (size_t)MP_DIM * C_DIM;           // [O, C] bf16, 2 MB

  // K0: transpose + cast
  dim3 g0((T_DIM + 31) / 32, C_DIM / 32, B_DIM);
  k_transpose<<<g0, dim3(32, 8), 0, stream>>>(x, xt);

  // KW: cast W to bf16
  k_cast_w<<<(O_DIM * C_DIM / 4) / 256, 256, 0, stream>>>((const float4*)W, Wb);

  // K1: v = xt * Wb^T  (256x128 tile, 504 blocks, 2 blocks/CU, 252 CUs)
  k_gemm_bf16<<<(MP_DIM / 256) * (O_DIM / 128), 512, 0, stream>>>(xt, Wb, v);

  // K2: fused filter + spike scan
  k_scan<<<BO_DIM / 64, 64, 0, stream>>>(v, out);
}